// Round 4
// baseline (412.760 us; speedup 1.0000x reference)
//
#include <hip/hip_runtime.h>

#define NC 10     // clusters
#define EMB 64
#define DD 1024
#define NP 4096   // patches per bag
#define NB 8      // batch
#define BP 128    // patches per block
#define KC 32     // k-chunk
#define NCHUNK (DD / KC)
#define SAS (KC + 4)          // As row stride (36 floats = 144B, 16B-aligned)
#define NBLK (NB * NP / BP)   // 256 K1 blocks
#define PPB (NP / BP)         // 32 partial blocks per bag

// ---------------- Kernel 1: e = relu(data @ W1^T + b1), fused segment sum ---
// 512 threads = 8 waves. Wave w: embs [8w,8w+8). Lane L: patches {L, L+64}.
// W streams through the scalar pipe (SGPR ping-pong prefetch); A double-buffered
// in LDS via register staging.
__global__ __launch_bounds__(512, 4) void embed_seg_kernel(
    const float* __restrict__ data, const int* __restrict__ labels,
    const float* __restrict__ W1, const float* __restrict__ b1,
    float* __restrict__ psum, float* __restrict__ pcnt, int use_atomic)
{
    __shared__ float As[2][BP][SAS];
    __shared__ float csum[NC][EMB];
    __shared__ float ccnt[NC];
    __shared__ int   labs[BP];

    const int t    = threadIdx.x;
    const int lane = t & 63;
    const int w    = t >> 6;
    const int bid  = blockIdx.x;
    const int b    = bid >> 5;             // bag (32 blocks per bag)
    const int p0   = (bid & 31) * BP;

    for (int i = t; i < NC * EMB; i += 512) (&csum[0][0])[i] = 0.f;
    if (t < NC) ccnt[t] = 0.f;
    if (t < BP) labs[t] = labels[b * NP + p0 + t];

    const int we = __builtin_amdgcn_readfirstlane(w << 3);
    const float* __restrict__ Wbase = W1 + (size_t)we * DD;
    const float* __restrict__ Ab    = data + (size_t)(b * NP + p0) * DD;

    // staging map: thread -> (rows sp, sp+64), k-offset sk
    const int sp = t >> 3;          // 0..63
    const int sk = (t & 7) << 2;    // 0..28

    // prologue: stage chunk 0
    float4 sa0 = *(const float4*)(Ab + (size_t)sp * DD + sk);
    float4 sa1 = *(const float4*)(Ab + (size_t)(sp + 64) * DD + sk);
    *(float4*)&As[0][sp][sk]      = sa0;
    *(float4*)&As[0][sp + 64][sk] = sa1;

    // W ping-pong prefetch (wave-uniform -> SGPRs)
    float4 wreg[2][8];
#pragma unroll
    for (int e = 0; e < 8; ++e)
        wreg[0][e] = *(const float4*)(Wbase + (size_t)e * DD);

    float acc0[8] = {}, acc1[8] = {};
    __syncthreads();

    for (int c = 0; c < NCHUNK; ++c) {
        const int buf = c & 1;
        if (c + 1 < NCHUNK) {   // issue next A chunk early (latency hidden under FMAs)
            sa0 = *(const float4*)(Ab + (size_t)sp * DD + (c + 1) * KC + sk);
            sa1 = *(const float4*)(Ab + (size_t)(sp + 64) * DD + (c + 1) * KC + sk);
        }
#pragma unroll
        for (int kq = 0; kq < 8; ++kq) {
            const int cur = kq & 1, nxt = cur ^ 1;
            const int gknext = c * KC + (kq + 1) * 4;
            if (gknext < DD) {
#pragma unroll
                for (int e = 0; e < 8; ++e)
                    wreg[nxt][e] = *(const float4*)(Wbase + (size_t)e * DD + gknext);
            }
            const float4 a0 = *(const float4*)&As[buf][lane][kq << 2];
            const float4 a1 = *(const float4*)&As[buf][lane + 64][kq << 2];
#pragma unroll
            for (int e = 0; e < 8; ++e) {
                const float4 wv = wreg[cur][e];
                acc0[e] = fmaf(a0.x, wv.x, acc0[e]);
                acc0[e] = fmaf(a0.y, wv.y, acc0[e]);
                acc0[e] = fmaf(a0.z, wv.z, acc0[e]);
                acc0[e] = fmaf(a0.w, wv.w, acc0[e]);
                acc1[e] = fmaf(a1.x, wv.x, acc1[e]);
                acc1[e] = fmaf(a1.y, wv.y, acc1[e]);
                acc1[e] = fmaf(a1.z, wv.z, acc1[e]);
                acc1[e] = fmaf(a1.w, wv.w, acc1[e]);
            }
        }
        __syncthreads();
        if (c + 1 < NCHUNK) {
            *(float4*)&As[buf ^ 1][sp][sk]      = sa0;
            *(float4*)&As[buf ^ 1][sp + 64][sk] = sa1;
        }
        __syncthreads();
    }

    // epilogue: bias + relu + per-cluster LDS accumulation
    const int lab0 = labs[lane], lab1 = labs[lane + 64];
#pragma unroll
    for (int e = 0; e < 8; ++e) {
        const float bb = b1[we + e];
        float v0 = fmaxf(acc0[e] + bb, 0.f);
        float v1 = fmaxf(acc1[e] + bb, 0.f);
        atomicAdd(&csum[lab0][we + e], v0);
        atomicAdd(&csum[lab1][we + e], v1);
    }
    if (w == 0) atomicAdd(&ccnt[labs[lane]], 1.0f);
    if (w == 1) atomicAdd(&ccnt[labs[lane + 64]], 1.0f);
    __syncthreads();

    if (use_atomic) {
        for (int i = t; i < NC * EMB; i += 512)
            atomicAdd(&psum[(size_t)b * NC * EMB + i], (&csum[0][0])[i]);
        if (t < NC) atomicAdd(&pcnt[b * NC + t], ccnt[t]);
    } else {
        for (int i = t; i < NC * EMB; i += 512)
            psum[(size_t)bid * NC * EMB + i] = (&csum[0][0])[i];
        if (t < NC) pcnt[bid * NC + t] = ccnt[t];
    }
}

// ---------------- Kernel 2: reduce partials, means, attention, softmax, fc6 --
// grid = NB blocks, 256 threads. npb = partial blocks per bag (PPB or 1).
__global__ __launch_bounds__(256) void head_kernel(
    const float* __restrict__ psum, const float* __restrict__ pcnt, int npb,
    const float* __restrict__ Wa1, const float* __restrict__ ba1,
    const float* __restrict__ Wa2, const float* __restrict__ ba2,
    const float* __restrict__ Wf1, const float* __restrict__ bf1,
    const float* __restrict__ Wf2, const float* __restrict__ bf2,
    float* __restrict__ out)
{
    __shared__ float h[NC][EMB];
    __shared__ float cnt_s[NC];
    __shared__ float mask[NC];
    __shared__ float att[NC][32];
    __shared__ float a_s[NC];
    __shared__ float A_s[NC];
    __shared__ float M_s[EMB];
    __shared__ float f_s[32];

    const int b = blockIdx.x;
    const int t = threadIdx.x;

    if (t < NC) {
        float s = 0.f;
        for (int pb = 0; pb < npb; ++pb) s += pcnt[(size_t)(b * npb + pb) * NC + t];
        cnt_s[t] = s;
        mask[t]  = s > 0.f ? 1.f : 0.f;
    }
    __syncthreads();
    for (int i = t; i < NC * EMB; i += 256) {
        float s = 0.f;
        for (int pb = 0; pb < npb; ++pb) s += psum[(size_t)(b * npb + pb) * NC * EMB + i];
        (&h[0][0])[i] = s / fmaxf(cnt_s[i >> 6], 1.f);
    }
    __syncthreads();

    for (int task = t; task < NC * 32; task += 256) {
        int c = task >> 5, hh = task & 31;
        float s = ba1[hh];
        for (int e = 0; e < EMB; ++e) s = fmaf(Wa1[hh * EMB + e], h[c][e], s);
        att[c][hh] = tanhf(s);
    }
    __syncthreads();

    if (t < NC) {
        float s = ba2[0];
        for (int hh = 0; hh < 32; ++hh) s = fmaf(Wa2[hh], att[t][hh], s);
        a_s[t] = s;
    }
    __syncthreads();

    if (t == 0) {
        // faithful to reference numeric trick
        float xmax = -1e30f;
        for (int c = 0; c < NC; ++c) {
            float xm = a_s[c] * mask[c] + (1.0f - 1.0f / (mask[c] + 1e-5f));
            xmax = fmaxf(xmax, xm);
        }
        float ex[NC], ssum = 0.f;
        for (int c = 0; c < NC; ++c) {
            ex[c] = expf(a_s[c] - xmax) * mask[c];
            ssum += ex[c];
        }
        for (int c = 0; c < NC; ++c) A_s[c] = ex[c] / ssum;
    }
    __syncthreads();

    if (t < EMB) {
        float s = 0.f;
        for (int c = 0; c < NC; ++c) s = fmaf(A_s[c], h[c][t], s);
        M_s[t] = s;
    }
    __syncthreads();

    if (t < 32) {
        float s = bf1[t];
        for (int e = 0; e < EMB; ++e) s = fmaf(Wf1[t * EMB + e], M_s[e], s);
        f_s[t] = fmaxf(s, 0.f);
    }
    __syncthreads();

    if (t == 0) {
        float s = bf2[0];
        for (int hh = 0; hh < 32; ++hh) s = fmaf(Wf2[hh], f_s[hh], s);
        out[b] = s;
    }
}

extern "C" void kernel_launch(void* const* d_in, const int* in_sizes, int n_in,
                              void* d_out, int out_size, void* d_ws, size_t ws_size,
                              hipStream_t stream)
{
    const float* data   = (const float*)d_in[0];
    const int*   labels = (const int*)  d_in[1];
    const float* W1     = (const float*)d_in[2];
    const float* b1     = (const float*)d_in[3];
    const float* Wa1    = (const float*)d_in[4];
    const float* ba1    = (const float*)d_in[5];
    const float* Wa2    = (const float*)d_in[6];
    const float* ba2    = (const float*)d_in[7];
    const float* Wf1    = (const float*)d_in[8];
    const float* bf1    = (const float*)d_in[9];
    const float* Wf2    = (const float*)d_in[10];
    const float* bf2    = (const float*)d_in[11];

    const size_t need = ((size_t)NBLK * NC * EMB + (size_t)NBLK * NC) * sizeof(float);
    float* psum = (float*)d_ws;

    if (ws_size >= need) {
        // atomic-free: per-block partials, no memset needed
        float* pcnt = psum + (size_t)NBLK * NC * EMB;
        embed_seg_kernel<<<NBLK, 512, 0, stream>>>(data, labels, W1, b1, psum, pcnt, 0);
        head_kernel<<<NB, 256, 0, stream>>>(psum, pcnt, PPB, Wa1, ba1, Wa2, ba2,
                                            Wf1, bf1, Wf2, bf2, (float*)d_out);
    } else {
        // fallback: global atomics into zeroed [NB][NC][EMB] + [NB][NC]
        float* pcnt = psum + (size_t)NB * NC * EMB;
        hipMemsetAsync(d_ws, 0, (size_t)(NB * NC * EMB + NB * NC) * sizeof(float), stream);
        embed_seg_kernel<<<NBLK, 512, 0, stream>>>(data, labels, W1, b1, psum, pcnt, 1);
        head_kernel<<<NB, 256, 0, stream>>>(psum, pcnt, 1, Wa1, ba1, Wa2, ba2,
                                            Wf1, bf1, Wf2, bf2, (float*)d_out);
    }
}

// Round 7
// 262.769 us; speedup vs baseline: 1.5708x; 1.5708x over previous
//
#include <hip/hip_runtime.h>
#include <stdint.h>

#define NC 10     // clusters
#define EMB 64
#define DD 1024
#define NP 4096   // patches per bag
#define NB 8      // batch
#define BP 128    // patches per block
#define NBLK (NB * NP / BP)   // 256 blocks
#define PPB (NP / BP)         // 32 partial blocks per bag
#define KCH 128               // k per chunk
#define NCHUNK (DD / KCH)     // 8
#define WFRAG_U32 65536       // 32 ksteps * 4 ct * 2 hl * 64 lanes * 4 u32 = 256KB

typedef __attribute__((ext_vector_type(4))) float f32x4;
typedef __attribute__((ext_vector_type(8))) short short8;

union FragU {
    uint32_t u[4];
    int4     i;
    short8   s;
};

// ---------- Prep: W1 fp32 -> bf16 hi/lo fragments in MFMA B-layout ----------
// row tid (16B each): tid = kg*512 + ct*128 + hl*64 + lane
// e = ct*16 + (lane&15), k = kg*32 + (lane>>4)*8 + j   (16x16x32 B-frag layout)
__global__ __launch_bounds__(256) void prep_wfrag(
    const float* __restrict__ W1, uint32_t* __restrict__ wf)
{
    const int tid  = blockIdx.x * 256 + threadIdx.x;   // 0..16383
    const int lane = tid & 63;
    const int hl   = (tid >> 6) & 1;
    const int ct   = (tid >> 7) & 3;
    const int kg   = tid >> 9;                         // 0..31
    const int e    = ct * 16 + (lane & 15);
    const int k0   = kg * 32 + (lane >> 4) * 8;
    const float* src = W1 + (size_t)e * DD + k0;

    uint32_t out[4];
#pragma unroll
    for (int q = 0; q < 4; ++q) {
        float x0 = src[2 * q], x1 = src[2 * q + 1];
        uint32_t b0 = __float_as_uint(x0), b1 = __float_as_uint(x1);
        uint32_t h0 = (b0 + 0x7fffu + ((b0 >> 16) & 1u)) >> 16;   // RNE bf16
        uint32_t h1 = (b1 + 0x7fffu + ((b1 >> 16) & 1u)) >> 16;
        if (hl == 0) {
            out[q] = h0 | (h1 << 16);
        } else {
            float r0 = x0 - __uint_as_float(h0 << 16);
            float r1 = x1 - __uint_as_float(h1 << 16);
            uint32_t c0 = __float_as_uint(r0), c1 = __float_as_uint(r1);
            uint32_t l0 = (c0 + 0x7fffu + ((c0 >> 16) & 1u)) >> 16;
            uint32_t l1 = (c1 + 0x7fffu + ((c1 >> 16) & 1u)) >> 16;
            out[q] = l0 | (l1 << 16);
        }
    }
    *(uint4*)(wf + (size_t)tid * 4) = make_uint4(out[0], out[1], out[2], out[3]);
}

// ---------- K1: e = relu(data @ W1^T + b1) via 3-term bf16 MFMA + seg-sum ----
// 256 blocks x 512 threads (8 waves). Wave w: patches [p0+16w, p0+16w+16),
// all 64 embs (ct=0..3). A per-lane from global; W frags LDS double-buffered.
__global__ __launch_bounds__(512, 2) void embed_mfma(
    const float* __restrict__ data, const int* __restrict__ labels,
    const uint32_t* __restrict__ wf, const float* __restrict__ b1,
    float* __restrict__ psum, float* __restrict__ pcnt, int use_atomic)
{
    __shared__ uint32_t wl[2][8192];      // 2 x 32KB W-frag chunk buffers
    __shared__ float csum[NC][EMB];
    __shared__ float ccnt[NC];
    __shared__ int   labs[BP];

    const int t    = threadIdx.x;
    const int lane = t & 63;
    const int w    = t >> 6;
    const int bid  = blockIdx.x;
    const int bag  = bid >> 5;
    const int p0   = (bid & 31) * BP;

    for (int i = t; i < NC * EMB; i += 512) (&csum[0][0])[i] = 0.f;
    if (t < NC) ccnt[t] = 0.f;
    if (t < BP) labs[t] = labels[bag * NP + p0 + t];

    // A: row = p0 + 16w + (lane&15); k-base = (lane>>4)*8
    const float* Ap = data + (size_t)(bag * NP + p0 + w * 16 + (lane & 15)) * DD
                    + ((lane >> 4) << 3);
    // W staging: thread covers u32 [t*16, t*16+16) of each 8192-u32 chunk
    const uint32_t* Wg = wf + (size_t)t * 16;

    f32x4 acc[4] = {};   // acc[ct]

    float4 aA[8], aB[8];     // A chunk ping-pong (8 x float4 = 32 fp32)
    uint4  wreg[4];          // W chunk staging regs

    // ---- prologue: load chunk 0 ----
#pragma unroll
    for (int ks = 0; ks < 4; ++ks) {
        aA[2 * ks]     = *(const float4*)(Ap + ks * 32);
        aA[2 * ks + 1] = *(const float4*)(Ap + ks * 32 + 4);
    }
#pragma unroll
    for (int q = 0; q < 4; ++q) wreg[q] = *(const uint4*)(Wg + q * 4);
#pragma unroll
    for (int q = 0; q < 4; ++q) *(uint4*)&wl[0][t * 16 + q * 4] = wreg[q];
    __syncthreads();

    // pack helpers (trunc split for A)
#define PACK_HI(x0, x1) ((__float_as_uint(x1) & 0xffff0000u) | (__float_as_uint(x0) >> 16))
#define SPLIT_KSTEP(ACUR, ks, ahi, alo)                                          \
    {                                                                            \
        const float4 a0 = ACUR[2 * (ks)], a1 = ACUR[2 * (ks) + 1];               \
        ahi.u[0] = PACK_HI(a0.x, a0.y);                                          \
        ahi.u[1] = PACK_HI(a0.z, a0.w);                                          \
        ahi.u[2] = PACK_HI(a1.x, a1.y);                                          \
        ahi.u[3] = PACK_HI(a1.z, a1.w);                                          \
        float r0 = a0.x - __uint_as_float(__float_as_uint(a0.x) & 0xffff0000u);  \
        float r1 = a0.y - __uint_as_float(__float_as_uint(a0.y) & 0xffff0000u);  \
        float r2 = a0.z - __uint_as_float(__float_as_uint(a0.z) & 0xffff0000u);  \
        float r3 = a0.w - __uint_as_float(__float_as_uint(a0.w) & 0xffff0000u);  \
        float r4 = a1.x - __uint_as_float(__float_as_uint(a1.x) & 0xffff0000u);  \
        float r5 = a1.y - __uint_as_float(__float_as_uint(a1.y) & 0xffff0000u);  \
        float r6 = a1.z - __uint_as_float(__float_as_uint(a1.z) & 0xffff0000u);  \
        float r7 = a1.w - __uint_as_float(__float_as_uint(a1.w) & 0xffff0000u);  \
        alo.u[0] = PACK_HI(r0, r1);                                              \
        alo.u[1] = PACK_HI(r2, r3);                                              \
        alo.u[2] = PACK_HI(r4, r5);                                              \
        alo.u[3] = PACK_HI(r6, r7);                                              \
    }

#define CHUNK_BODY(c, BUF, ACUR, ANEXT)                                          \
    {                                                                            \
        if ((c) + 1 < NCHUNK) {                                                  \
            _Pragma("unroll")                                                    \
            for (int ks = 0; ks < 4; ++ks) {                                     \
                ANEXT[2 * ks]     = *(const float4*)(Ap + ((c) + 1) * KCH + ks * 32);      \
                ANEXT[2 * ks + 1] = *(const float4*)(Ap + ((c) + 1) * KCH + ks * 32 + 4);  \
            }                                                                    \
            _Pragma("unroll")                                                    \
            for (int q = 0; q < 4; ++q)                                          \
                wreg[q] = *(const uint4*)(Wg + ((size_t)((c) + 1)) * 8192 + q * 4);        \
        }                                                                        \
        _Pragma("unroll")                                                        \
        for (int ks = 0; ks < 4; ++ks) {                                         \
            FragU ahi, alo;                                                      \
            SPLIT_KSTEP(ACUR, ks, ahi, alo);                                     \
            _Pragma("unroll")                                                    \
            for (int ct = 0; ct < 4; ++ct) {                                     \
                FragU bhi, blo;                                                  \
                bhi.i = *(const int4*)&wl[BUF][((ks * 4 + ct) * 2 + 0) * 256 + lane * 4];  \
                blo.i = *(const int4*)&wl[BUF][((ks * 4 + ct) * 2 + 1) * 256 + lane * 4];  \
                acc[ct] = __builtin_amdgcn_mfma_f32_16x16x32_bf16(ahi.s, bhi.s, acc[ct], 0, 0, 0); \
                acc[ct] = __builtin_amdgcn_mfma_f32_16x16x32_bf16(ahi.s, blo.s, acc[ct], 0, 0, 0); \
                acc[ct] = __builtin_amdgcn_mfma_f32_16x16x32_bf16(alo.s, bhi.s, acc[ct], 0, 0, 0); \
            }                                                                    \
        }                                                                        \
        if ((c) + 1 < NCHUNK) {                                                  \
            _Pragma("unroll")                                                    \
            for (int q = 0; q < 4; ++q)                                          \
                *(uint4*)&wl[(BUF) ^ 1][t * 16 + q * 4] = wreg[q];               \
        }                                                                        \
        __syncthreads();                                                         \
    }

    CHUNK_BODY(0, 0, aA, aB)
    CHUNK_BODY(1, 1, aB, aA)
    CHUNK_BODY(2, 0, aA, aB)
    CHUNK_BODY(3, 1, aB, aA)
    CHUNK_BODY(4, 0, aA, aB)
    CHUNK_BODY(5, 1, aB, aA)
    CHUNK_BODY(6, 0, aA, aB)
    CHUNK_BODY(7, 1, aB, aA)

    // ---- epilogue: bias + relu + per-cluster LDS accumulation ----
    // D-frag: col(emb) = ct*16 + (lane&15), row(patch) = w*16 + (lane>>4)*4 + r
    float b1v[4];
#pragma unroll
    for (int ct = 0; ct < 4; ++ct) b1v[ct] = b1[ct * 16 + (lane & 15)];
#pragma unroll
    for (int ct = 0; ct < 4; ++ct) {
#pragma unroll
        for (int r = 0; r < 4; ++r) {
            const int patch = w * 16 + (lane >> 4) * 4 + r;
            float v = fmaxf(acc[ct][r] + b1v[ct], 0.f);
            atomicAdd(&csum[labs[patch]][ct * 16 + (lane & 15)], v);
        }
    }
    if (t < BP) atomicAdd(&ccnt[labs[t]], 1.0f);
    __syncthreads();

    if (use_atomic) {
        for (int i = t; i < NC * EMB; i += 512)
            atomicAdd(&psum[(size_t)bag * NC * EMB + i], (&csum[0][0])[i]);
        if (t < NC) atomicAdd(&pcnt[bag * NC + t], ccnt[t]);
    } else {
        for (int i = t; i < NC * EMB; i += 512)
            psum[(size_t)bid * NC * EMB + i] = (&csum[0][0])[i];
        if (t < NC) pcnt[bid * NC + t] = ccnt[t];
    }
}

// ---------- K2: reduce partials, means, attention, masked softmax, fc6 ------
__global__ __launch_bounds__(256) void head_kernel(
    const float* __restrict__ psum, const float* __restrict__ pcnt, int npb,
    const float* __restrict__ Wa1, const float* __restrict__ ba1,
    const float* __restrict__ Wa2, const float* __restrict__ ba2,
    const float* __restrict__ Wf1, const float* __restrict__ bf1,
    const float* __restrict__ Wf2, const float* __restrict__ bf2,
    float* __restrict__ out)
{
    __shared__ float h[NC][EMB];
    __shared__ float cnt_s[NC];
    __shared__ float mask[NC];
    __shared__ float att[NC][32];
    __shared__ float a_s[NC];
    __shared__ float A_s[NC];
    __shared__ float M_s[EMB];
    __shared__ float f_s[32];

    const int b = blockIdx.x;
    const int t = threadIdx.x;

    if (t < NC) {
        float s = 0.f;
        for (int pb = 0; pb < npb; ++pb) s += pcnt[(size_t)(b * npb + pb) * NC + t];
        cnt_s[t] = s;
        mask[t]  = s > 0.f ? 1.f : 0.f;
    }
    __syncthreads();
    for (int i = t; i < NC * EMB; i += 256) {
        float s = 0.f;
        for (int pb = 0; pb < npb; ++pb) s += psum[(size_t)(b * npb + pb) * NC * EMB + i];
        (&h[0][0])[i] = s / fmaxf(cnt_s[i >> 6], 1.f);
    }
    __syncthreads();

    for (int task = t; task < NC * 32; task += 256) {
        int c = task >> 5, hh = task & 31;
        float s = ba1[hh];
        for (int e = 0; e < EMB; ++e) s = fmaf(Wa1[hh * EMB + e], h[c][e], s);
        att[c][hh] = tanhf(s);
    }
    __syncthreads();

    if (t < NC) {
        float s = ba2[0];
        for (int hh = 0; hh < 32; ++hh) s = fmaf(Wa2[hh], att[t][hh], s);
        a_s[t] = s;
    }
    __syncthreads();

    if (t == 0) {
        // faithful to reference numeric trick
        float xmax = -1e30f;
        for (int c = 0; c < NC; ++c) {
            float xm = a_s[c] * mask[c] + (1.0f - 1.0f / (mask[c] + 1e-5f));
            xmax = fmaxf(xmax, xm);
        }
        float ex[NC], ssum = 0.f;
        for (int c = 0; c < NC; ++c) {
            ex[c] = expf(a_s[c] - xmax) * mask[c];
            ssum += ex[c];
        }
        for (int c = 0; c < NC; ++c) A_s[c] = ex[c] / ssum;
    }
    __syncthreads();

    if (t < EMB) {
        float s = 0.f;
        for (int c = 0; c < NC; ++c) s = fmaf(A_s[c], h[c][t], s);
        M_s[t] = s;
    }
    __syncthreads();

    if (t < 32) {
        float s = bf1[t];
        for (int e = 0; e < EMB; ++e) s = fmaf(Wf1[t * EMB + e], M_s[e], s);
        f_s[t] = fmaxf(s, 0.f);
    }
    __syncthreads();

    if (t == 0) {
        float s = bf2[0];
        for (int hh = 0; hh < 32; ++hh) s = fmaf(Wf2[hh], f_s[hh], s);
        out[b] = s;
    }
}

extern "C" void kernel_launch(void* const* d_in, const int* in_sizes, int n_in,
                              void* d_out, int out_size, void* d_ws, size_t ws_size,
                              hipStream_t stream)
{
    const float* data   = (const float*)d_in[0];
    const int*   labels = (const int*)  d_in[1];
    const float* W1     = (const float*)d_in[2];
    const float* b1     = (const float*)d_in[3];
    const float* Wa1    = (const float*)d_in[4];
    const float* ba1    = (const float*)d_in[5];
    const float* Wa2    = (const float*)d_in[6];
    const float* ba2    = (const float*)d_in[7];
    const float* Wf1    = (const float*)d_in[8];
    const float* bf1    = (const float*)d_in[9];
    const float* Wf2    = (const float*)d_in[10];
    const float* bf2    = (const float*)d_in[11];

    uint32_t* wfrag = (uint32_t*)d_ws;                       // 256KB
    float* psum = (float*)(wfrag + WFRAG_U32);

    prep_wfrag<<<64, 256, 0, stream>>>(W1, wfrag);

    const size_t need_na = (size_t)WFRAG_U32 * 4 +
                           ((size_t)NBLK * NC * EMB + (size_t)NBLK * NC) * sizeof(float);
    if (ws_size >= need_na) {
        float* pcnt = psum + (size_t)NBLK * NC * EMB;
        embed_mfma<<<NBLK, 512, 0, stream>>>(data, labels, wfrag, b1, psum, pcnt, 0);
        head_kernel<<<NB, 256, 0, stream>>>(psum, pcnt, PPB, Wa1, ba1, Wa2, ba2,
                                            Wf1, bf1, Wf2, bf2, (float*)d_out);
    } else {
        float* pcnt = psum + (size_t)NB * NC * EMB;
        hipMemsetAsync((void*)psum, 0,
                       (size_t)(NB * NC * EMB + NB * NC) * sizeof(float), stream);
        embed_mfma<<<NBLK, 512, 0, stream>>>(data, labels, wfrag, b1, psum, pcnt, 1);
        head_kernel<<<NB, 256, 0, stream>>>(psum, pcnt, 1, Wa1, ba1, Wa2, ba2,
                                            Wf1, bf1, Wf2, bf2, (float*)d_out);
    }
}